// Round 1
// baseline (1548.667 us; speedup 1.0000x reference)
//
#include <hip/hip_runtime.h>

#define NROWS 65536
#define SB 256  // stride of the main ws activation buffer

__device__ __forceinline__ float frelu(float v) { return fmaxf(v, 0.f); }

// ---------------- prep kernels (run every call; deterministic) ----------------

// repack enc_w1 [128][165] -> [128][168] zero-padded (16B-aligned rows)
__global__ void repack_w1_k(const float* __restrict__ w, float* __restrict__ wp) {
  int idx = blockIdx.x * 256 + threadIdx.x;
  if (idx >= 128 * 168) return;
  int o = idx / 168, c = idx % 168;
  wp[idx] = (c < 165) ? w[o * 165 + c] : 0.f;
}

// transposed codebooks: etg[l][k][d] = embeds[l][d][k]
__global__ void prep_etg_k(const float* __restrict__ embeds, float* __restrict__ etg) {
  int idx = blockIdx.x * 256 + threadIdx.x;
  if (idx >= 4 * 512 * 64) return;
  int d = idx & 63;
  int k = (idx >> 6) & 511;
  int l = idx >> 15;
  etg[idx] = embeds[(l * 64 + d) * 512 + k];
}

// en2[l][k] = sum_d embeds[l][d][k]^2
__global__ void prep_en2_k(const float* __restrict__ embeds, float* __restrict__ en2) {
  int idx = blockIdx.x * 256 + threadIdx.x;
  if (idx >= 4 * 512) return;
  int l = idx >> 9, k = idx & 511;
  float s = 0.f;
  for (int d = 0; d < 64; ++d) {
    float e = embeds[(l * 64 + d) * 512 + k];
    s = fmaf(e, e, s);
  }
  en2[idx] = s;
}

__global__ void zero_dsum_k(float* d) {
  if (threadIdx.x == 0 && blockIdx.x == 0) *d = 0.f;
}

// ---------------- fused 1x1-conv kernel ----------------
// 128 rows/block, 512 threads (8 waves). lanes = output channels (oi*64+lane),
// wave w owns rows w*16..w*16+15. Activations staged in LDS; LDS reads are
// wave-uniform broadcasts (conflict-free); global stores coalesced (lane = o).
// Safe in-place (in == out): all reads land in LDS before the barrier.
template <int CIN, int CINP, int COUT, int INSTRIDE, int OUTSTRIDE, bool RELU_IN, bool RELU_OUT>
__global__ __launch_bounds__(512) void conv_k(const float* in, const float* __restrict__ w,
                                              const float* __restrict__ b, float* out) {
  constexpr int TN = (COUT + 63) / 64;
  constexpr bool OG = (COUT % 64) != 0;
  __shared__ float xs[128][CINP];
  const int tid = threadIdx.x;
  const int lane = tid & 63;
  const int wv = tid >> 6;
  const long row0 = (long)blockIdx.x * 128;

  for (int rj = 0; rj < 16; ++rj) {
    const int r = wv * 16 + rj;
    const float* src = in + (row0 + r) * (long)INSTRIDE;
    for (int c = lane; c < CINP; c += 64) {
      float v = (c < CIN) ? src[c] : 0.f;
      if (RELU_IN) v = frelu(v);
      xs[r][c] = v;
    }
  }
  __syncthreads();

  float acc[16][TN];
#pragma unroll
  for (int i = 0; i < 16; ++i)
#pragma unroll
    for (int j = 0; j < TN; ++j) acc[i][j] = 0.f;

#pragma unroll 2
  for (int q = 0; q < CINP / 4; ++q) {
    const int c = q * 4;
    float4 wq[TN];
#pragma unroll
    for (int oi = 0; oi < TN; ++oi) {
      const int o = oi * 64 + lane;
      if (!OG || o < COUT)
        wq[oi] = *(const float4*)(w + (long)o * CINP + c);
      else
        wq[oi] = make_float4(0.f, 0.f, 0.f, 0.f);
    }
#pragma unroll
    for (int rj = 0; rj < 16; ++rj) {
      const float4 x = *(const float4*)(&xs[wv * 16 + rj][c]);
#pragma unroll
      for (int oi = 0; oi < TN; ++oi) {
        acc[rj][oi] = fmaf(x.x, wq[oi].x, acc[rj][oi]);
        acc[rj][oi] = fmaf(x.y, wq[oi].y, acc[rj][oi]);
        acc[rj][oi] = fmaf(x.z, wq[oi].z, acc[rj][oi]);
        acc[rj][oi] = fmaf(x.w, wq[oi].w, acc[rj][oi]);
      }
    }
  }

#pragma unroll
  for (int oi = 0; oi < TN; ++oi) {
    const int o = oi * 64 + lane;
    if (OG && o >= COUT) continue;
    const float bias = b[o];
#pragma unroll
    for (int rj = 0; rj < 16; ++rj) {
      float v = acc[rj][oi] + bias;
      if (RELU_OUT) v = frelu(v);
      out[(row0 + wv * 16 + rj) * (long)OUTSTRIDE + o] = v;
    }
  }
}

// ---------------- fused ResBlock (256 -> 32 -> 256 + residual) ----------------
__global__ __launch_bounds__(512) void resblock_k(const float* in, const float* __restrict__ wa,
                                                  const float* __restrict__ ba,
                                                  const float* __restrict__ wb,
                                                  const float* __restrict__ bb, float* out) {
  __shared__ float xs[128][256];
  __shared__ float ts[128][36];
  const int tid = threadIdx.x;
  const int lane = tid & 63;
  const int wv = tid >> 6;
  const long row0 = (long)blockIdx.x * 128;

  for (int rj = 0; rj < 16; ++rj) {
    const int r = wv * 16 + rj;
    const float* src = in + (row0 + r) * (long)SB;
    for (int c = lane; c < 256; c += 64) xs[r][c] = src[c];
  }
  __syncthreads();

  // phase A: t = relu(wa . relu(x) + ba), 32 outputs. lanes split: o = lane&31, row-half = lane>>5
  {
    const int o = lane & 31;
    const int rh = lane >> 5;
    float acc[8];
#pragma unroll
    for (int i = 0; i < 8; ++i) acc[i] = 0.f;
#pragma unroll 2
    for (int q = 0; q < 64; ++q) {
      const int c = q * 4;
      const float4 wq = *(const float4*)(wa + o * 256 + c);
#pragma unroll
      for (int rjj = 0; rjj < 8; ++rjj) {
        const int r = wv * 16 + rh * 8 + rjj;
        const float4 x = *(const float4*)(&xs[r][c]);
        acc[rjj] = fmaf(frelu(x.x), wq.x, acc[rjj]);
        acc[rjj] = fmaf(frelu(x.y), wq.y, acc[rjj]);
        acc[rjj] = fmaf(frelu(x.z), wq.z, acc[rjj]);
        acc[rjj] = fmaf(frelu(x.w), wq.w, acc[rjj]);
      }
    }
    const float bias = ba[o];
#pragma unroll
    for (int rjj = 0; rjj < 8; ++rjj) {
      const int r = wv * 16 + rh * 8 + rjj;
      ts[r][o] = frelu(acc[rjj] + bias);
    }
  }
  __syncthreads();

  // phase B: out = x + wb . t + bb, 256 outputs
  float acc2[16][4];
#pragma unroll
  for (int i = 0; i < 16; ++i)
#pragma unroll
    for (int j = 0; j < 4; ++j) acc2[i][j] = 0.f;

#pragma unroll
  for (int q = 0; q < 8; ++q) {
    const int c = q * 4;
    float4 wq[4];
#pragma unroll
    for (int oi = 0; oi < 4; ++oi) wq[oi] = *(const float4*)(wb + (oi * 64 + lane) * 32 + c);
#pragma unroll
    for (int rj = 0; rj < 16; ++rj) {
      const float4 t4 = *(const float4*)(&ts[wv * 16 + rj][c]);
#pragma unroll
      for (int oi = 0; oi < 4; ++oi) {
        acc2[rj][oi] = fmaf(t4.x, wq[oi].x, acc2[rj][oi]);
        acc2[rj][oi] = fmaf(t4.y, wq[oi].y, acc2[rj][oi]);
        acc2[rj][oi] = fmaf(t4.z, wq[oi].z, acc2[rj][oi]);
        acc2[rj][oi] = fmaf(t4.w, wq[oi].w, acc2[rj][oi]);
      }
    }
  }
#pragma unroll
  for (int oi = 0; oi < 4; ++oi) {
    const int o = oi * 64 + lane;
    const float bias = bb[o];
#pragma unroll
    for (int rj = 0; rj < 16; ++rj) {
      const int r = wv * 16 + rj;
      out[(row0 + r) * (long)SB + o] = xs[r][o] + acc2[rj][oi] + bias;
    }
  }
}

// ---------------- residual VQ (4 levels, exact fp32 argmin) ----------------
// 32 rows/block, 256 threads (4 waves, 8 rows/wave). Codebook staged per
// (level, 256-k chunk) in LDS in natural [d][k] layout (conflict-free).
// score = en2[k] - 2*res.e_k  (||res||^2 is argmin-invariant).
// First-min tie-break identical to jnp.argmin. q gathered coalesced from etg.
__global__ __launch_bounds__(256) void vq_k(float* buf, const float* __restrict__ embeds,
                                            const float* __restrict__ en2,
                                            const float* __restrict__ etg,
                                            float* __restrict__ dsum) {
  __shared__ float resL[32][68];
  __shared__ float et[64][260];
  const int tid = threadIdx.x;
  const int lane = tid & 63;
  const int wv = tid >> 6;
  const long row0 = (long)blockIdx.x * 32;

  for (int rj = 0; rj < 8; ++rj) {
    const int r = wv * 8 + rj;
    resL[r][lane] = buf[(row0 + r) * (long)SB + lane];
  }
  __syncthreads();

  float dloc = 0.f;

  for (int l = 0; l < 4; ++l) {
    float best[8];
    int bk[8];
#pragma unroll
    for (int i = 0; i < 8; ++i) {
      best[i] = 3.4e38f;
      bk[i] = 0;
    }

    for (int kc = 0; kc < 2; ++kc) {
      // stage et[64][256] <- embeds[l][:, kc*256 .. kc*256+255]
      for (int i = tid; i < 64 * 256; i += 256) {
        const int d = i >> 8, kk = i & 255;
        et[d][kk] = embeds[((l * 64 + d) << 9) + (kc << 8) + kk];
      }
      __syncthreads();

      float acc[8][4];
#pragma unroll
      for (int i = 0; i < 8; ++i)
#pragma unroll
        for (int j = 0; j < 4; ++j) acc[i][j] = 0.f;

      for (int dq = 0; dq < 16; ++dq) {
        float4 x4[8];
#pragma unroll
        for (int rj = 0; rj < 8; ++rj) x4[rj] = *(const float4*)(&resL[wv * 8 + rj][dq * 4]);
#pragma unroll
        for (int dd = 0; dd < 4; ++dd) {
          const float4 e4 = *(const float4*)(&et[dq * 4 + dd][lane * 4]);
#pragma unroll
          for (int rj = 0; rj < 8; ++rj) {
            const float xv = dd == 0 ? x4[rj].x : dd == 1 ? x4[rj].y : dd == 2 ? x4[rj].z : x4[rj].w;
            acc[rj][0] = fmaf(xv, e4.x, acc[rj][0]);
            acc[rj][1] = fmaf(xv, e4.y, acc[rj][1]);
            acc[rj][2] = fmaf(xv, e4.z, acc[rj][2]);
            acc[rj][3] = fmaf(xv, e4.w, acc[rj][3]);
          }
        }
      }

      const float4 e2 = *(const float4*)(en2 + l * 512 + kc * 256 + lane * 4);
#pragma unroll
      for (int rj = 0; rj < 8; ++rj) {
#pragma unroll
        for (int j = 0; j < 4; ++j) {
          const float ev = j == 0 ? e2.x : j == 1 ? e2.y : j == 2 ? e2.z : e2.w;
          const float s = fmaf(-2.f, acc[rj][j], ev);
          const int k = kc * 256 + lane * 4 + j;
          if (s < best[rj]) {
            best[rj] = s;
            bk[rj] = k;
          }
        }
      }
      __syncthreads();  // et reused next chunk/level
    }

    // cross-lane first-min argmin
#pragma unroll
    for (int rj = 0; rj < 8; ++rj) {
      float bv = best[rj];
      int bi = bk[rj];
#pragma unroll
      for (int m = 1; m < 64; m <<= 1) {
        const float ov = __shfl_xor(bv, m, 64);
        const int ok = __shfl_xor(bi, m, 64);
        if (ov < bv || (ov == bv && ok < bi)) {
          bv = ov;
          bi = ok;
        }
      }
      bk[rj] = bi;
    }

    // gather + straight-through update
#pragma unroll
    for (int rj = 0; rj < 8; ++rj) {
      const int r = wv * 8 + rj;
      const float q = etg[((long)((l << 9) + bk[rj])) * 64 + lane];
      const float res = resL[r][lane];
      const float t = q - res;        // q_raw - res (used for diff)
      const float qst = res + t;      // straight-through forward value
      dloc = fmaf(t, t, dloc);
      resL[r][lane] = res - qst;
      if (l == 0) buf[(row0 + r) * (long)SB + lane] = qst;  // main_q
    }
  }

#pragma unroll
  for (int m = 1; m < 64; m <<= 1) dloc += __shfl_xor(dloc, m, 64);
  if (lane == 0) atomicAdd(dsum, dloc);
}

__global__ void finalize_k(const float* __restrict__ dsum, float* __restrict__ out) {
  if (threadIdx.x == 0 && blockIdx.x == 0)
    out[0] = *dsum * (1.0f / (4.0f * 65536.0f * 64.0f));
}

// ---------------- launch ----------------
extern "C" void kernel_launch(void* const* d_in, const int* in_sizes, int n_in, void* d_out,
                              int out_size, void* d_ws, size_t ws_size, hipStream_t stream) {
  (void)in_sizes; (void)n_in; (void)out_size; (void)ws_size;
  const float* x = (const float*)d_in[0];
  const float* enc_w1 = (const float*)d_in[1];
  const float* enc_b1 = (const float*)d_in[2];
  const float* enc_w2 = (const float*)d_in[3];
  const float* enc_b2 = (const float*)d_in[4];
  const float* enc_w3 = (const float*)d_in[5];
  const float* enc_b3 = (const float*)d_in[6];
  const float* enc_res_wa = (const float*)d_in[7];
  const float* enc_res_ba = (const float*)d_in[8];
  const float* enc_res_wb = (const float*)d_in[9];
  const float* enc_res_bb = (const float*)d_in[10];
  const float* q_w = (const float*)d_in[11];
  const float* q_b = (const float*)d_in[12];
  const float* embeds = (const float*)d_in[13];
  const float* dec_w1 = (const float*)d_in[14];
  const float* dec_b1 = (const float*)d_in[15];
  const float* dec_res_wa = (const float*)d_in[16];
  const float* dec_res_ba = (const float*)d_in[17];
  const float* dec_res_wb = (const float*)d_in[18];
  const float* dec_res_bb = (const float*)d_in[19];
  const float* dec_w2 = (const float*)d_in[20];
  const float* dec_b2 = (const float*)d_in[21];
  const float* dec_w3 = (const float*)d_in[22];
  const float* dec_b3 = (const float*)d_in[23];

  float* ws = (float*)d_ws;
  float* buf = ws;                       // [N][256]
  float* wpad = ws + (long)NROWS * SB;   // 128*168
  float* etg = wpad + 128 * 168;         // 4*512*64
  float* en2 = etg + 4 * 512 * 64;       // 4*512
  float* dsum = en2 + 4 * 512;           // 1

  float* dout = (float*)d_out;

  repack_w1_k<<<(128 * 168 + 255) / 256, 256, 0, stream>>>(enc_w1, wpad);
  prep_etg_k<<<(4 * 512 * 64 + 255) / 256, 256, 0, stream>>>(embeds, etg);
  prep_en2_k<<<(4 * 512 + 255) / 256, 256, 0, stream>>>(embeds, en2);
  zero_dsum_k<<<1, 64, 0, stream>>>(dsum);

  const int GB = NROWS / 128;  // 512 blocks for conv/resblock kernels

  // encoder
  conv_k<165, 168, 128, 165, SB, false, true><<<GB, 512, 0, stream>>>(x, wpad, enc_b1, buf);
  conv_k<128, 128, 256, SB, SB, false, true><<<GB, 512, 0, stream>>>(buf, enc_w2, enc_b2, buf);
  conv_k<256, 256, 256, SB, SB, false, false><<<GB, 512, 0, stream>>>(buf, enc_w3, enc_b3, buf);
  resblock_k<<<GB, 512, 0, stream>>>(buf, enc_res_wa, enc_res_ba, enc_res_wb, enc_res_bb, buf);
  resblock_k<<<GB, 512, 0, stream>>>(buf, enc_res_wa + 8192, enc_res_ba + 32, enc_res_wb + 8192,
                                     enc_res_bb + 256, buf);
  conv_k<256, 256, 64, SB, SB, true, false><<<GB, 512, 0, stream>>>(buf, q_w, q_b, buf);

  // residual VQ
  vq_k<<<NROWS / 32, 256, 0, stream>>>(buf, embeds, en2, etg, dsum);

  // decoder
  conv_k<64, 64, 256, SB, SB, false, false><<<GB, 512, 0, stream>>>(buf, dec_w1, dec_b1, buf);
  resblock_k<<<GB, 512, 0, stream>>>(buf, dec_res_wa, dec_res_ba, dec_res_wb, dec_res_bb, buf);
  resblock_k<<<GB, 512, 0, stream>>>(buf, dec_res_wa + 8192, dec_res_ba + 32, dec_res_wb + 8192,
                                     dec_res_bb + 256, buf);
  conv_k<256, 256, 128, SB, SB, true, true><<<GB, 512, 0, stream>>>(buf, dec_w2, dec_b2, buf);
  conv_k<128, 128, 165, SB, 165, false, false><<<GB, 512, 0, stream>>>(buf, dec_w3, dec_b3, dout);

  finalize_k<<<1, 64, 0, stream>>>(dsum, dout + (long)NROWS * 165);
}